// Round 3
// baseline (149.724 us; speedup 1.0000x reference)
//
#include <hip/hip_runtime.h>
#include <math.h>

namespace {
constexpr int Bn = 2, Sn = 2048, INn = 512, HDn = 32, Hn = 16;
constexpr int NQ = Bn * Hn * Sn * HDn;           // 2097152 bf16 elems per Q/K/V tensor
// ws offsets in FLOAT units — all regions DISJOINT
constexpr int OFF_WBB = 2490368;    // Weff B-frags bf16: 786432 bf16 -> 393216 fl
constexpr int OFF_BEFF = 2883584;   // 1536 fl
constexpr int OFF_QKV = 2885120;    // Q,K,V swizzled bf16: 3*2097152 -> 3145728 fl
constexpr int OFF_FB = 7079424;     // F A-frags bf16 -> 1048576 fl
constexpr int OFF_WOB = 8128000;    // Wo B-frags bf16 -> 131072 fl
constexpr float LOG2E = 1.44269504f;
}

typedef __attribute__((ext_vector_type(8))) short s8v;   // 8 bf16 in 4 VGPRs
typedef __attribute__((ext_vector_type(4))) float f4v;   // MFMA accumulator / float4

__device__ __forceinline__ unsigned short f2bf(float x) {
  unsigned u = __float_as_uint(x);
  return (unsigned short)((u + 0x8000u) >> 16);
}

// pack 8 f32 -> 8 bf16 (RNE) via v_cvt_pk_bf16_f32
__device__ __forceinline__ s8v pack8(const f4v& lo, const f4v& hi) {
  union { unsigned u[4]; s8v v; } r;
  asm("v_cvt_pk_bf16_f32 %0, %1, %2" : "=v"(r.u[0]) : "v"(lo[0]), "v"(lo[1]));
  asm("v_cvt_pk_bf16_f32 %0, %1, %2" : "=v"(r.u[1]) : "v"(lo[2]), "v"(lo[3]));
  asm("v_cvt_pk_bf16_f32 %0, %1, %2" : "=v"(r.u[2]) : "v"(hi[0]), "v"(hi[1]));
  asm("v_cvt_pk_bf16_f32 %0, %1, %2" : "=v"(r.u[3]) : "v"(hi[2]), "v"(hi[3]));
  return r.v;
}

// ========== K1: weff_direct (LDS-staged MFMA) + beff + woconv (flat 432) ==========
__global__ __launch_bounds__(256)
void stage1_kernel(const float* __restrict__ Wl, const float* __restrict__ bl,
                   const float* __restrict__ Wq, const float* __restrict__ Wk,
                   const float* __restrict__ Wv, const float* __restrict__ Wo,
                   unsigned short* __restrict__ wbb, float* __restrict__ beff,
                   unsigned short* __restrict__ wob) {
  const int bid = blockIdx.x;
  const int t = threadIdx.x;
  __shared__ __align__(16) unsigned short ws_sh[8192];   // 16 KB union
  if (bid < 256) {
    // ---- weff_direct ----
    const int bx = bid & 15, h = bid >> 4;
    const int lane = t & 63, w = t >> 6;
    const int n = lane & 15, quad = lane >> 4;
    const int nt0 = (w >> 1) * 3;
    unsigned short* a_sh = ws_sh;          // [4][512]  (it_sub*2+kc_sub)
    unsigned short* b_sh = ws_sh + 2048;   // [12][512] (kc_sub*6+nt)
    f4v acc[3] = {};
    for (int ot = 0; ot < 8; ++ot) {
      __syncthreads();   // previous chunk's reads done
      // stage A: Wl[h][o(64)][i(32)] -> transposed bf16 A-frags (float4 loads)
#pragma unroll
      for (int k = 0; k < 2; ++k) {
        int vidx = t + k * 256;            // 0..511
        int ol = vidx >> 3, il4 = (vidx & 7) * 4;
        f4v v4 = *(const f4v*)&Wl[(size_t)(h * INn + ot * 64 + ol) * INn + bx * 32 + il4];
#pragma unroll
        for (int j = 0; j < 4; ++j) {
          int il = il4 + j;
          int dst = (((il >> 4) * 2 + (ol >> 5)) * 64 + ((ol >> 3) & 3) * 16 + (il & 15)) * 8 + (ol & 7);
          a_sh[dst] = f2bf(v4[j]);
        }
      }
      // stage B: Wq/Wk/Wv[h][o(64)][32] -> bf16 B-frags (K pre-scaled by log2e), float4 loads
#pragma unroll
      for (int which = 0; which < 3; ++which) {
        const float* Wx = which == 0 ? Wq : (which == 1 ? Wk : Wv);
        const float scale = (which == 1) ? LOG2E : 1.0f;
#pragma unroll
        for (int k = 0; k < 2; ++k) {
          int vidx = t + k * 256;          // 0..511
          int ol = vidx >> 3, dd4 = (vidx & 7) * 4;
          f4v v4 = *(const f4v*)&Wx[(size_t)(h * INn + ot * 64 + ol) * HDn + dd4];
          int nt = which * 2 + (dd4 >> 4);
#pragma unroll
          for (int j = 0; j < 4; ++j) {
            int dd = dd4 + j;
            int dst = (((ol >> 5) * 6 + nt) * 64 + ((ol >> 3) & 3) * 16 + (dd & 15)) * 8 + (ol & 7);
            b_sh[dst] = f2bf(v4[j] * scale);
          }
        }
      }
      __syncthreads();
      const s8v* av = (const s8v*)a_sh;
      const s8v* bv = (const s8v*)b_sh;
#pragma unroll
      for (int kc_sub = 0; kc_sub < 2; ++kc_sub) {
        s8v a = av[((w & 1) * 2 + kc_sub) * 64 + lane];
#pragma unroll
        for (int q = 0; q < 3; ++q)
          acc[q] = __builtin_amdgcn_mfma_f32_16x16x32_bf16(
              a, bv[(kc_sub * 6 + nt0 + q) * 64 + lane], acc[q], 0, 0, 0);
      }
    }
    // epilogue: C -> LDS (stride 97) -> B-frag coalesced stores
    __syncthreads();
    unsigned short* clds = ws_sh;   // 32*97 ushort
#pragma unroll
    for (int q = 0; q < 3; ++q)
#pragma unroll
      for (int reg = 0; reg < 4; ++reg) {
        int i_local = (w & 1) * 16 + quad * 4 + reg;
        int n96 = (nt0 + q) * 16 + n;
        clds[i_local * 97 + n96] = f2bf(acc[q][reg]);
      }
    __syncthreads();
    s8v* wbbv = (s8v*)wbb;
    for (int nt = w; nt < 6; nt += 4) {
      s8v v;
#pragma unroll
      for (int j = 0; j < 8; j++)
        v[j] = (short)clds[((lane >> 4) * 8 + j) * 97 + nt * 16 + (lane & 15)];
      wbbv[((h * 16 + bx) * 6 + nt) * 64 + lane] = v;
    }
  } else if (bid < 304) {
    // ---- beff ----
    const int v0 = bid - 256;         // 0..47
    const int h = v0 & 15, which = v0 >> 4;
    const float* Wx = which == 0 ? Wq : (which == 1 ? Wk : Wv);
    const float scale = (which == 1) ? LOG2E : 1.0f;
    const int d = t & 31, oc = t >> 5;
    float p = 0.f;
    for (int k = 0; k < 64; k++) {
      int o = oc * 64 + k;
      p += bl[h * INn + o] * Wx[(h * INn + o) * HDn + d];
    }
    float* red = (float*)ws_sh;
    red[t] = p;
    __syncthreads();
    if (t < 32) {
      float s = 0.f;
#pragma unroll
      for (int k = 0; k < 8; k++) s += red[t + 32 * k];
      beff[which * (Hn * HDn) + h * HDn + t] = s * scale;
    }
  } else {
    // ---- woconv: Wo -> B-frags ----
    const int tid = (bid - 304) * 256 + t;      // 0..32767
    const int lane = tid & 63;
    const int kn = tid >> 6;
    const int kc = kn >> 5, nt = kn & 31;
    const float* src = Wo + (size_t)(nt * 16 + (lane & 15)) * INn + kc * 32 + (lane >> 4) * 8;
    unsigned short* dst = wob + (size_t)tid * 8;
#pragma unroll
    for (int j = 0; j < 8; j++) dst[j] = f2bf(src[j]);
  }
}

// ================= K2: QKV projection: LDS-staged-B MFMA GEMM, x converted on the fly ======
// grid (32,16): each block does 128 rows (2 row-tiles per wave) of one head.
// B (Weff frags, 96 KB/head) staged via global_load_lds, dbuf 2x12KB.
// A: x rows loaded as 2x float4/lane, packed to bf16 frags with v_cvt_pk_bf16_f32.
__global__ __launch_bounds__(256)
void qkv_mfma_kernel(const float* __restrict__ x,
                     const unsigned short* __restrict__ wbb_u,
                     const float* __restrict__ beff,
                     unsigned short* __restrict__ qkv) {
  const int rt32 = blockIdx.x;  // 0..31 -> rows [rt32*128, +128)
  const int h = blockIdx.y;     // 16
  const int t = threadIdx.x;
  const int lane = t & 63, w = t >> 6;
  const int n = lane & 15, quad = lane >> 4;
  __shared__ __align__(16) unsigned short bsh[2][6144];   // 2 bufs x 12 KB (2 kc x 6 frags)
  const int rtA = rt32 * 8 + w;        // half-0 row-tile of this wave
  const int rtB = rt32 * 8 + 4 + w;    // half-1 row-tile
  const float* xA = x + (size_t)(rtA * 16 + (lane & 15)) * INn + (lane >> 4) * 8;
  const float* xB = x + (size_t)(rtB * 16 + (lane & 15)) * INn + (lane >> 4) * 8;

  const char* wsrc = (const char*)wbb_u + (size_t)h * 16 * 6 * 64 * 16;
  // stage chunk c (kc = 2c,2c+1): 12288 B; lds dest = wave-uniform base + lane*16 (linear)
  auto stage = [&](int buf, int c) {
    const char* src = wsrc + (size_t)c * 12288 + (size_t)lane * 16;
    char* dst = (char*)bsh[buf];
#pragma unroll
    for (int j = 0; j < 3; ++j) {
      int off = (w * 3 + j) * 1024;
      __builtin_amdgcn_global_load_lds(
          (const __attribute__((address_space(1))) void*)(src + off),
          (__attribute__((address_space(3))) void*)(dst + off), 16, 0, 0);
    }
  };

  f4v acc[2][6] = {};
  f4v pA[2][2], pB[2][2];   // raw f32 prefetch [ks][lo/hi]
  s8v a0[2], a1[2];
#pragma unroll
  for (int ks = 0; ks < 2; ++ks) {
    pA[ks][0] = *(const f4v*)(xA + ks * 32);
    pA[ks][1] = *(const f4v*)(xA + ks * 32 + 4);
    pB[ks][0] = *(const f4v*)(xB + ks * 32);
    pB[ks][1] = *(const f4v*)(xB + ks * 32 + 4);
  }
  stage(0, 0);
#pragma unroll
  for (int ks = 0; ks < 2; ++ks) {
    a0[ks] = pack8(pA[ks][0], pA[ks][1]);
    a1[ks] = pack8(pB[ks][0], pB[ks][1]);
  }
  __syncthreads();   // implicit vmcnt(0) drain -> buf0 ready
  for (int c = 0; c < 8; ++c) {
    const int buf = c & 1;
    if (c < 7) {
      stage(buf ^ 1, c + 1);
#pragma unroll
      for (int ks = 0; ks < 2; ++ks) {
        int kc = (c + 1) * 2 + ks;
        pA[ks][0] = *(const f4v*)(xA + kc * 32);
        pA[ks][1] = *(const f4v*)(xA + kc * 32 + 4);
        pB[ks][0] = *(const f4v*)(xB + kc * 32);
        pB[ks][1] = *(const f4v*)(xB + kc * 32 + 4);
      }
    }
    const s8v* bb = (const s8v*)bsh[buf];
#pragma unroll
    for (int ks = 0; ks < 2; ++ks) {
#pragma unroll
      for (int nt = 0; nt < 6; ++nt) {
        s8v b = bb[(ks * 6 + nt) * 64 + lane];
        acc[0][nt] = __builtin_amdgcn_mfma_f32_16x16x32_bf16(a0[ks], b, acc[0][nt], 0, 0, 0);
        acc[1][nt] = __builtin_amdgcn_mfma_f32_16x16x32_bf16(a1[ks], b, acc[1][nt], 0, 0, 0);
      }
    }
    __syncthreads();   // drains next-chunk stage; protects WAR on buf^1
    if (c < 7) {
#pragma unroll
      for (int ks = 0; ks < 2; ++ks) {
        a0[ks] = pack8(pA[ks][0], pA[ks][1]);
        a1[ks] = pack8(pB[ks][0], pB[ks][1]);
      }
    }
  }
  // epilogue: reuse bsh[0] (12 KB) as swizzle-assembly LDS, one 64-row group per half
  unsigned short* eld = bsh[0];
  const s8v* eldv = (const s8v*)eld;
  for (int half = 0; half < 2; ++half) {
    __syncthreads();   // prior reads of bsh/eld complete
#pragma unroll
    for (int nt = 0; nt < 6; ++nt) {
      const int which = nt >> 1;
      const int dd = (nt & 1) * 16 + n;
      const float bias = beff[which * 512 + h * 32 + dd];
#pragma unroll
      for (int reg = 0; reg < 4; ++reg) {
        const int kl = w * 16 + quad * 4 + reg;
        unsigned short val = f2bf(acc[half][nt][reg] + bias);
        int off;
        if (which == 0) {
          off = (((kl >> 4) * 4 + (dd >> 3)) * 16 + (kl & 15)) * 8 + (dd & 7);
        } else if (which == 1) {
          int f = ((kl >> 5) << 1) | ((kl >> 2) & 1);
          int mm = ((kl >> 3) & 3) * 4 + (kl & 3);
          off = ((f * 4 + (dd >> 3)) * 16 + mm) * 8 + (dd & 7);
        } else {
          off = ((((kl >> 5) * 2 + (dd >> 4)) * 4 + ((kl >> 3) & 3)) * 16 + (dd & 15)) * 8 + (kl & 7);
        }
        eld[which * 2048 + off] = val;
      }
    }
    __syncthreads();
    const int rt64 = rt32 * 2 + half;
    const int b = rt64 >> 5;
    const int ts = rt64 & 31;
    const size_t tilebase = ((size_t)((b * Hn + h) * 32) + ts) * 2048;  // bf16 units
#pragma unroll
    for (int cc = 0; cc < 3; ++cc) {
      int idx = cc * 256 + t;            // 0..767
      int which = idx >> 8, k8 = idx & 255;
      *((s8v*)(qkv + (size_t)which * NQ + tilebase) + k8) = eldv[idx];
    }
  }
}

// ================= K3: MFMA flash attention, fixed-base softmax =================
__device__ __forceinline__ void tile_step(
    bool diag, int w, int n, int quad,
    const s8v& qf, const s8v& kf0, const s8v& kf1, const s8v& kf2, const s8v& kf3,
    const s8v& vf00, const s8v& vf01, const s8v& vf10, const s8v& vf11,
    float& lp, f4v& O0, f4v& O1) {
  const f4v zero{};
  __builtin_amdgcn_s_setprio(1);
  f4v s0 = __builtin_amdgcn_mfma_f32_16x16x32_bf16(kf0, qf, zero, 0, 0, 0);
  f4v s1 = __builtin_amdgcn_mfma_f32_16x16x32_bf16(kf1, qf, zero, 0, 0, 0);
  f4v s2 = __builtin_amdgcn_mfma_f32_16x16x32_bf16(kf2, qf, zero, 0, 0, 0);
  f4v s3 = __builtin_amdgcn_mfma_f32_16x16x32_bf16(kf3, qf, zero, 0, 0, 0);
  __builtin_amdgcn_s_setprio(0);
  float p[16];
#pragma unroll
  for (int r = 0; r < 4; ++r) {
    p[0 * 4 + r] = s0[r];
    p[1 * 4 + r] = s1[r];
    p[2 * 4 + r] = s2[r];
    p[3 * 4 + r] = s3[r];
  }
  if (diag) {
    int qa = w * 16 + n;
#pragma unroll
    for (int f = 0; f < 4; ++f)
#pragma unroll
      for (int r = 0; r < 4; ++r) {
        int ka = ((f >> 1) << 5) + quad * 8 + ((f & 1) << 2) + r;
        if (ka > qa) p[f * 4 + r] = -1e30f;
      }
  }
#pragma unroll
  for (int i = 0; i < 16; ++i)
    p[i] = __builtin_amdgcn_exp2f(p[i]);   // scores pre-scaled by log2e; masked -> 0
  // tree-sum (depth 4) instead of 16-deep serial chain
  float q0 = (p[0] + p[1]) + (p[2] + p[3]);
  float q1 = (p[4] + p[5]) + (p[6] + p[7]);
  float q2 = (p[8] + p[9]) + (p[10] + p[11]);
  float q3 = (p[12] + p[13]) + (p[14] + p[15]);
  lp += (q0 + q1) + (q2 + q3);
  // packed f32->bf16: 8 cvt_pk instrs replace the manual add/shift/pack sequence
  union { unsigned u[4]; s8v v; } P0, P1;
#pragma unroll
  for (int j = 0; j < 4; ++j) {
    asm("v_cvt_pk_bf16_f32 %0, %1, %2" : "=v"(P0.u[j]) : "v"(p[2 * j]), "v"(p[2 * j + 1]));
    asm("v_cvt_pk_bf16_f32 %0, %1, %2" : "=v"(P1.u[j]) : "v"(p[8 + 2 * j]), "v"(p[8 + 2 * j + 1]));
  }
  __builtin_amdgcn_s_setprio(1);
  O0 = __builtin_amdgcn_mfma_f32_16x16x32_bf16(P0.v, vf00, O0, 0, 0, 0);
  O0 = __builtin_amdgcn_mfma_f32_16x16x32_bf16(P1.v, vf10, O0, 0, 0, 0);
  O1 = __builtin_amdgcn_mfma_f32_16x16x32_bf16(P0.v, vf01, O1, 0, 0, 0);
  O1 = __builtin_amdgcn_mfma_f32_16x16x32_bf16(P1.v, vf11, O1, 0, 0, 0);
  __builtin_amdgcn_s_setprio(0);
}

__device__ __forceinline__ void attn_write(
    unsigned short* __restrict__ fb, int bh, int qt, int w, int n, int quad,
    float l, const f4v& O0, const f4v& O1) {
  float linv = 1.f / l;
  const int b = bh >> 4, h = bh & 15;
#pragma unroll
  for (int r = 0; r < 4; ++r) {
    float lr = __shfl(linv, quad * 4 + r, 64);
    int qabs = qt * 64 + w * 16 + quad * 4 + r;
    int rglob = b * 2048 + qabs;
    int rt16 = rglob >> 4, m = rglob & 15;
    size_t base = (size_t)(rt16 * 16 + h) * 512;
    fb[base + ((n >> 3) * 16 + m) * 8 + (n & 7)] = f2bf(O0[r] * lr);
    fb[base + ((2 + (n >> 3)) * 16 + m) * 8 + (n & 7)] = f2bf(O1[r] * lr);
  }
}

// grid (16,32): paired q-tiles (qp, 31-qp); direct-global Q frags; dbuf K/V LDS,
// one barrier per k-tile; 2-deep register prefetch pipeline.
__global__ __launch_bounds__(256, 2)
void attn_kernel(const unsigned short* __restrict__ qkv_bf, unsigned short* __restrict__ fb) {
  const int qp = blockIdx.x;   // 0..15
  const int bh = blockIdx.y;   // 0..31
  const int qtA = qp, qtB = 31 - qp;
  const int t = threadIdx.x;
  const int lane = t & 63, w = t >> 6;
  const int n = lane & 15, quad = lane >> 4;
  __shared__ s8v kv_sh[2][512];   // [buf][k:256 | v:256] = 16 KB
  const s8v* Qs = (const s8v*)qkv_bf + (size_t)bh * 32 * 256;
  const s8v* Ks = (const s8v*)(qkv_bf + NQ) + (size_t)bh * 32 * 256;
  const s8v* Vs = (const s8v*)(qkv_bf + 2 * NQ) + (size_t)bh * 32 * 256;
  s8v qfA = Qs[qtA * 256 + w * 64 + lane];
  s8v qfB = Qs[qtB * 256 + w * 64 + lane];
  f4v OA0{}, OA1{}, OB0{}, OB1{};
  float lpA = 0.f, lpB = 0.f;
  s8v k0 = Ks[t], v0 = Vs[t];
  s8v k1, v1;
  if (qtB >= 1) { k1 = Ks[256 + t]; v1 = Vs[256 + t]; }
  for (int kt = 0; kt <= qtB; ++kt) {
    const int c = kt & 1;
    kv_sh[c][t] = k0;
    kv_sh[c][256 + t] = v0;
    __syncthreads();
    k0 = k1; v0 = v1;
    if (kt + 2 <= qtB) {
      k1 = Ks[(kt + 2) * 256 + t];
      v1 = Vs[(kt + 2) * 256 + t];
    }
    const s8v* kb = kv_sh[c];
    const s8v* vb = kb + 256;
    s8v kf0 = kb[lane], kf1 = kb[64 + lane], kf2 = kb[128 + lane], kf3 = kb[192 + lane];
    s8v vf00 = vb[lane], vf01 = vb[64 + lane], vf10 = vb[128 + lane], vf11 = vb[192 + lane];
    if (kt <= qtA)
      tile_step(kt == qtA, w, n, quad, qfA, kf0, kf1, kf2, kf3,
                vf00, vf01, vf10, vf11, lpA, OA0, OA1);
    tile_step(kt == qtB, w, n, quad, qfB, kf0, kf1, kf2, kf3,
              vf00, vf01, vf10, vf11, lpB, OB0, OB1);
  }
  lpA += __shfl_xor(lpA, 16); lpA += __shfl_xor(lpA, 32);
  lpB += __shfl_xor(lpB, 16); lpB += __shfl_xor(lpB, 32);
  attn_write(fb, bh, qtA, w, n, quad, lpA, OA0, OA1);
  attn_write(fb, bh, qtB, w, n, quad, lpB, OB0, OB1);
}

// ================= K4: output projection: LDS-staged-B MFMA GEMM =================
// grid (64,8): each block 64 rows x 64 cols; B staged in 2-kc chunks (8 KB), dbuf.
__global__ __launch_bounds__(256)
void outproj_mfma_kernel(const unsigned short* __restrict__ fb_u,
                         const unsigned short* __restrict__ wob_u,
                         const float* __restrict__ bo,
                         float* __restrict__ out) {
  const int rt64 = blockIdx.x;  // 64
  const int jt = blockIdx.y;    // 8 (4 n-frags each)
  const int t = threadIdx.x;
  const int lane = t & 63, w = t >> 6;
  const int n = lane & 15, quad = lane >> 4;
  const s8v* fbv = (const s8v*)fb_u;
  const int rt16 = rt64 * 4 + w;
  __shared__ __align__(16) unsigned short bsh[2][4096];  // 2 x 8 KB (2 kc per chunk)
  // stage chunk c = kc pair (2c, 2c+1); each wave w stages frag (jt*4+w) of each kc
  auto stage = [&](int buf, int c) {
#pragma unroll
    for (int j = 0; j < 2; ++j) {
      const int idx0 = j * 256 + w * 64;           // wave-uniform dest elem base
      const int kc = 2 * c + j;
      const char* src = (const char*)wob_u
                        + ((size_t)((kc * 32 + jt * 4 + w) * 64)) * 16 + (size_t)lane * 16;
      char* dst = (char*)bsh[buf] + (size_t)idx0 * 16;
      __builtin_amdgcn_global_load_lds(
          (const __attribute__((address_space(1))) void*)src,
          (__attribute__((address_space(3))) void*)dst, 16, 0, 0);
    }
  };
  f4v acc[4] = {};
  s8v a0 = fbv[((size_t)rt16 * 16 + 0) * 64 + lane];
  s8v a1 = fbv[((size_t)rt16 * 16 + 1) * 64 + lane];
  stage(0, 0);
  __syncthreads();
  for (int c = 0; c < 8; ++c) {
    const int buf = c & 1;
    if (c < 7) stage(buf ^ 1, c + 1);
    s8v na0, na1;
    if (c < 7) {
      na0 = fbv[((size_t)rt16 * 16 + 2 * c + 2) * 64 + lane];
      na1 = fbv[((size_t)rt16 * 16 + 2 * c + 3) * 64 + lane];
    }
    const s8v* bb = (const s8v*)bsh[buf];
#pragma unroll
    for (int i = 0; i < 4; ++i)
      acc[i] = __builtin_amdgcn_mfma_f32_16x16x32_bf16(a0, bb[i * 64 + lane], acc[i], 0, 0, 0);
#pragma unroll
    for (int i = 0; i < 4; ++i)
      acc[i] = __builtin_amdgcn_mfma_f32_16x16x32_bf16(a1, bb[(4 + i) * 64 + lane], acc[i], 0, 0, 0);
    __syncthreads();
    if (c < 7) { a0 = na0; a1 = na1; }
  }
#pragma unroll
  for (int i = 0; i < 4; ++i) {
    const int j = jt * 64 + i * 16 + n;
    const float bias = bo[j];
#pragma unroll
    for (int reg = 0; reg < 4; ++reg) {
      int r = rt64 * 64 + w * 16 + quad * 4 + reg;
      out[(size_t)r * INn + j] = acc[i][reg] + bias;
    }
  }
}

extern "C" void kernel_launch(void* const* d_in, const int* in_sizes, int n_in,
                              void* d_out, int out_size, void* d_ws, size_t ws_size,
                              hipStream_t stream) {
  const float* x  = (const float*)d_in[0];
  const float* Wl = (const float*)d_in[1];
  const float* bl = (const float*)d_in[2];
  const float* Wq = (const float*)d_in[3];
  const float* Wk = (const float*)d_in[4];
  const float* Wv = (const float*)d_in[5];
  const float* Wo = (const float*)d_in[6];
  const float* bo = (const float*)d_in[7];
  float* ws = (float*)d_ws;
  float* out = (float*)d_out;
  unsigned short* wbb = (unsigned short*)(ws + OFF_WBB);
  float*          beff = ws + OFF_BEFF;
  unsigned short* qkv = (unsigned short*)(ws + OFF_QKV);
  unsigned short* fb  = (unsigned short*)(ws + OFF_FB);
  unsigned short* wob = (unsigned short*)(ws + OFF_WOB);

  stage1_kernel<<<dim3(432), 256, 0, stream>>>(Wl, bl, Wq, Wk, Wv, Wo, wbb, beff, wob);
  qkv_mfma_kernel<<<dim3(32, Hn), 256, 0, stream>>>(x, wbb, beff, qkv);
  attn_kernel<<<dim3(16, 32), 256, 0, stream>>>(qkv, fb);
  outproj_mfma_kernel<<<dim3(64, 8), 256, 0, stream>>>(fb, wob, bo, out);
}

// Round 4
// 132.163 us; speedup vs baseline: 1.1329x; 1.1329x over previous
//
#include <hip/hip_runtime.h>
#include <math.h>

namespace {
constexpr int Bn = 2, Sn = 2048, INn = 512, HDn = 32, Hn = 16;
constexpr int NQ = Bn * Hn * Sn * HDn;           // 2097152 bf16 elems per Q/K/V tensor
// ws offsets in FLOAT units — all regions DISJOINT
constexpr int OFF_WBB = 2490368;    // Weff B-frags bf16: 786432 bf16 -> 393216 fl
constexpr int OFF_BEFF = 2883584;   // 1536 fl
constexpr int OFF_QKV = 2885120;    // Q,K,V swizzled bf16: 3*2097152 -> 3145728 fl
constexpr int OFF_XB = 6030848;     // x A-frags bf16 -> 1048576 fl
constexpr int OFF_FB = 7079424;     // F A-frags bf16 -> 1048576 fl
constexpr int OFF_WOB = 8128000;    // Wo B-frags bf16 -> 131072 fl
constexpr float LOG2E = 1.44269504f;
}

typedef __attribute__((ext_vector_type(8))) short s8v;   // 8 bf16 in 4 VGPRs
typedef __attribute__((ext_vector_type(4))) float f4v;   // MFMA accumulator

__device__ __forceinline__ unsigned short f2bf(float x) {
  unsigned u = __float_as_uint(x);
  return (unsigned short)((u + 0x8000u) >> 16);
}

// ========== K1: weff_direct (LDS-staged MFMA) + beff + xconv + woconv (flat 1456) ==========
__global__ __launch_bounds__(256)
void stage1_kernel(const float* __restrict__ Wl, const float* __restrict__ bl,
                   const float* __restrict__ Wq, const float* __restrict__ Wk,
                   const float* __restrict__ Wv,
                   const float* __restrict__ x, const float* __restrict__ Wo,
                   unsigned short* __restrict__ wbb, float* __restrict__ beff,
                   unsigned short* __restrict__ xb, unsigned short* __restrict__ wob) {
  const int bid = blockIdx.x;
  const int t = threadIdx.x;
  __shared__ __align__(16) unsigned short ws_sh[8192];   // 16 KB union
  if (bid < 256) {
    // ---- weff_direct ----
    const int bx = bid & 15, h = bid >> 4;
    const int lane = t & 63, w = t >> 6;
    const int n = lane & 15, quad = lane >> 4;
    const int nt0 = (w >> 1) * 3;
    unsigned short* a_sh = ws_sh;          // [4][512]  (it_sub*2+kc_sub)
    unsigned short* b_sh = ws_sh + 2048;   // [12][512] (kc_sub*6+nt)
    f4v acc[3] = {};
    for (int ot = 0; ot < 8; ++ot) {
      __syncthreads();   // previous chunk's reads done
      // stage A: Wl[h][o(64)][i(32)] -> transposed bf16 A-frags
#pragma unroll
      for (int k = 0; k < 8; ++k) {
        int idx = t + k * 256;
        int ol = idx >> 5, il = idx & 31;
        float v = Wl[(size_t)(h * INn + ot * 64 + ol) * INn + bx * 32 + il];
        int dst = (((il >> 4) * 2 + (ol >> 5)) * 64 + ((ol >> 3) & 3) * 16 + (il & 15)) * 8 + (ol & 7);
        a_sh[dst] = f2bf(v);
      }
      // stage B: Wq/Wk/Wv[h][o(64)][32] -> bf16 B-frags (K pre-scaled by log2e)
#pragma unroll
      for (int which = 0; which < 3; ++which) {
        const float* Wx = which == 0 ? Wq : (which == 1 ? Wk : Wv);
        const float scale = (which == 1) ? LOG2E : 1.0f;
#pragma unroll
        for (int k = 0; k < 8; ++k) {
          int idx = t + k * 256;
          int ol = idx >> 5, dd = idx & 31;
          float v = Wx[(size_t)(h * INn + ot * 64 + ol) * HDn + dd] * scale;
          int nt = which * 2 + (dd >> 4);
          int dst = (((ol >> 5) * 6 + nt) * 64 + ((ol >> 3) & 3) * 16 + (dd & 15)) * 8 + (ol & 7);
          b_sh[dst] = f2bf(v);
        }
      }
      __syncthreads();
      const s8v* av = (const s8v*)a_sh;
      const s8v* bv = (const s8v*)b_sh;
#pragma unroll
      for (int kc_sub = 0; kc_sub < 2; ++kc_sub) {
        s8v a = av[((w & 1) * 2 + kc_sub) * 64 + lane];
#pragma unroll
        for (int q = 0; q < 3; ++q)
          acc[q] = __builtin_amdgcn_mfma_f32_16x16x32_bf16(
              a, bv[(kc_sub * 6 + nt0 + q) * 64 + lane], acc[q], 0, 0, 0);
      }
    }
    // epilogue: C -> LDS (stride 97) -> B-frag coalesced stores
    __syncthreads();
    unsigned short* clds = ws_sh;   // 32*97 ushort
#pragma unroll
    for (int q = 0; q < 3; ++q)
#pragma unroll
      for (int reg = 0; reg < 4; ++reg) {
        int i_local = (w & 1) * 16 + quad * 4 + reg;
        int n96 = (nt0 + q) * 16 + n;
        clds[i_local * 97 + n96] = f2bf(acc[q][reg]);
      }
    __syncthreads();
    s8v* wbbv = (s8v*)wbb;
    for (int nt = w; nt < 6; nt += 4) {
      s8v v;
#pragma unroll
      for (int j = 0; j < 8; j++)
        v[j] = (short)clds[((lane >> 4) * 8 + j) * 97 + nt * 16 + (lane & 15)];
      wbbv[((h * 16 + bx) * 6 + nt) * 64 + lane] = v;
    }
  } else if (bid < 304) {
    // ---- beff ----
    const int v0 = bid - 256;         // 0..47
    const int h = v0 & 15, which = v0 >> 4;
    const float* Wx = which == 0 ? Wq : (which == 1 ? Wk : Wv);
    const float scale = (which == 1) ? LOG2E : 1.0f;
    const int d = t & 31, oc = t >> 5;
    float p = 0.f;
    for (int k = 0; k < 64; k++) {
      int o = oc * 64 + k;
      p += bl[h * INn + o] * Wx[(h * INn + o) * HDn + d];
    }
    float* red = (float*)ws_sh;
    red[t] = p;
    __syncthreads();
    if (t < 32) {
      float s = 0.f;
#pragma unroll
      for (int k = 0; k < 8; k++) s += red[t + 32 * k];
      beff[which * (Hn * HDn) + h * HDn + t] = s * scale;
    }
  } else if (bid < 1328) {
    // ---- xconv: x -> A-frags ----
    const int tid = (bid - 304) * 256 + t;      // 0..262143
    const int lane = tid & 63;
    const int rk = tid >> 6;
    const int rt16 = rk >> 4, kc = rk & 15;
    const float* src = x + (size_t)(rt16 * 16 + (lane & 15)) * INn + kc * 32 + (lane >> 4) * 8;
    unsigned short* dst = xb + (size_t)tid * 8;
#pragma unroll
    for (int j = 0; j < 8; j++) dst[j] = f2bf(src[j]);
  } else {
    // ---- woconv: Wo -> B-frags ----
    const int tid = (bid - 1328) * 256 + t;     // 0..32767
    const int lane = tid & 63;
    const int kn = tid >> 6;
    const int kc = kn >> 5, nt = kn & 31;
    const float* src = Wo + (size_t)(nt * 16 + (lane & 15)) * INn + kc * 32 + (lane >> 4) * 8;
    unsigned short* dst = wob + (size_t)tid * 8;
#pragma unroll
    for (int j = 0; j < 8; j++) dst[j] = f2bf(src[j]);
  }
}

// ================= K2: QKV projection: LDS-staged-B MFMA GEMM =================
// grid (32,16): each block does 128 rows (2 row-tiles per wave) of one head.
// B (Weff frags, 96 KB/head) staged once per block via global_load_lds, dbuf 2x12KB.
__global__ __launch_bounds__(256)
void qkv_mfma_kernel(const unsigned short* __restrict__ xb_u,
                     const unsigned short* __restrict__ wbb_u,
                     const float* __restrict__ beff,
                     unsigned short* __restrict__ qkv) {
  const int rt32 = blockIdx.x;  // 0..31 -> rows [rt32*128, +128)
  const int h = blockIdx.y;     // 16
  const int t = threadIdx.x;
  const int lane = t & 63, w = t >> 6;
  const int n = lane & 15, quad = lane >> 4;
  const s8v* xbv = (const s8v*)xb_u;
  __shared__ __align__(16) unsigned short bsh[2][6144];   // 2 bufs x 12 KB (2 kc x 6 frags)
  const int rtA = rt32 * 8 + w;        // half-0 row-tile of this wave
  const int rtB = rt32 * 8 + 4 + w;    // half-1 row-tile

  const char* wsrc = (const char*)wbb_u + (size_t)h * 16 * 6 * 64 * 16;
  // stage chunk c (kc = 2c,2c+1): 12288 B; lds dest = wave-uniform base + lane*16 (linear)
  auto stage = [&](int buf, int c) {
    const char* src = wsrc + (size_t)c * 12288 + (size_t)lane * 16;
    char* dst = (char*)bsh[buf];
#pragma unroll
    for (int j = 0; j < 3; ++j) {
      int off = (w * 3 + j) * 1024;
      __builtin_amdgcn_global_load_lds(
          (const __attribute__((address_space(1))) void*)(src + off),
          (__attribute__((address_space(3))) void*)(dst + off), 16, 0, 0);
    }
  };

  f4v acc[2][6] = {};
  s8v a0[2], a1[2];
#pragma unroll
  for (int ks = 0; ks < 2; ++ks) {
    a0[ks] = xbv[((size_t)rtA * 16 + ks) * 64 + lane];
    a1[ks] = xbv[((size_t)rtB * 16 + ks) * 64 + lane];
  }
  stage(0, 0);
  __syncthreads();   // implicit vmcnt(0) drain -> buf0 ready
  for (int c = 0; c < 8; ++c) {
    const int buf = c & 1;
    if (c < 7) stage(buf ^ 1, c + 1);
    s8v na0[2], na1[2];
    if (c < 7) {
#pragma unroll
      for (int ks = 0; ks < 2; ++ks) {
        int kc = (c + 1) * 2 + ks;
        na0[ks] = xbv[((size_t)rtA * 16 + kc) * 64 + lane];
        na1[ks] = xbv[((size_t)rtB * 16 + kc) * 64 + lane];
      }
    }
    const s8v* bb = (const s8v*)bsh[buf];
#pragma unroll
    for (int ks = 0; ks < 2; ++ks) {
#pragma unroll
      for (int nt = 0; nt < 6; ++nt) {
        s8v b = bb[(ks * 6 + nt) * 64 + lane];
        acc[0][nt] = __builtin_amdgcn_mfma_f32_16x16x32_bf16(a0[ks], b, acc[0][nt], 0, 0, 0);
        acc[1][nt] = __builtin_amdgcn_mfma_f32_16x16x32_bf16(a1[ks], b, acc[1][nt], 0, 0, 0);
      }
    }
    __syncthreads();   // drains next-chunk stage; protects WAR on buf^1
    if (c < 7) {
#pragma unroll
      for (int ks = 0; ks < 2; ++ks) { a0[ks] = na0[ks]; a1[ks] = na1[ks]; }
    }
  }
  // epilogue: reuse bsh[0] (12 KB) as swizzle-assembly LDS, one 64-row group per half
  unsigned short* eld = bsh[0];
  const s8v* eldv = (const s8v*)eld;
  for (int half = 0; half < 2; ++half) {
    __syncthreads();   // prior reads of bsh/eld complete
#pragma unroll
    for (int nt = 0; nt < 6; ++nt) {
      const int which = nt >> 1;
      const int dd = (nt & 1) * 16 + n;
      const float bias = beff[which * 512 + h * 32 + dd];
#pragma unroll
      for (int reg = 0; reg < 4; ++reg) {
        const int kl = w * 16 + quad * 4 + reg;
        unsigned short val = f2bf(acc[half][nt][reg] + bias);
        int off;
        if (which == 0) {
          off = (((kl >> 4) * 4 + (dd >> 3)) * 16 + (kl & 15)) * 8 + (dd & 7);
        } else if (which == 1) {
          int f = ((kl >> 5) << 1) | ((kl >> 2) & 1);
          int mm = ((kl >> 3) & 3) * 4 + (kl & 3);
          off = ((f * 4 + (dd >> 3)) * 16 + mm) * 8 + (dd & 7);
        } else {
          off = ((((kl >> 5) * 2 + (dd >> 4)) * 4 + ((kl >> 3) & 3)) * 16 + (dd & 15)) * 8 + (kl & 7);
        }
        eld[which * 2048 + off] = val;
      }
    }
    __syncthreads();
    const int rt64 = rt32 * 2 + half;
    const int b = rt64 >> 5;
    const int ts = rt64 & 31;
    const size_t tilebase = ((size_t)((b * Hn + h) * 32) + ts) * 2048;  // bf16 units
#pragma unroll
    for (int cc = 0; cc < 3; ++cc) {
      int idx = cc * 256 + t;            // 0..767
      int which = idx >> 8, k8 = idx & 255;
      *((s8v*)(qkv + (size_t)which * NQ + tilebase) + k8) = eldv[idx];
    }
  }
}

// ================= K3: MFMA flash attention, fixed-base softmax =================
__device__ __forceinline__ void tile_step(
    bool diag, int w, int n, int quad,
    const s8v& qf, const s8v& kf0, const s8v& kf1, const s8v& kf2, const s8v& kf3,
    const s8v& vf00, const s8v& vf01, const s8v& vf10, const s8v& vf11,
    float& lp, f4v& O0, f4v& O1) {
  const f4v zero{};
  __builtin_amdgcn_s_setprio(1);
  f4v s0 = __builtin_amdgcn_mfma_f32_16x16x32_bf16(kf0, qf, zero, 0, 0, 0);
  f4v s1 = __builtin_amdgcn_mfma_f32_16x16x32_bf16(kf1, qf, zero, 0, 0, 0);
  f4v s2 = __builtin_amdgcn_mfma_f32_16x16x32_bf16(kf2, qf, zero, 0, 0, 0);
  f4v s3 = __builtin_amdgcn_mfma_f32_16x16x32_bf16(kf3, qf, zero, 0, 0, 0);
  __builtin_amdgcn_s_setprio(0);
  float p[16];
#pragma unroll
  for (int r = 0; r < 4; ++r) {
    p[0 * 4 + r] = s0[r];
    p[1 * 4 + r] = s1[r];
    p[2 * 4 + r] = s2[r];
    p[3 * 4 + r] = s3[r];
  }
  if (diag) {
    int qa = w * 16 + n;
#pragma unroll
    for (int f = 0; f < 4; ++f)
#pragma unroll
      for (int r = 0; r < 4; ++r) {
        int ka = ((f >> 1) << 5) + quad * 8 + ((f & 1) << 2) + r;
        if (ka > qa) p[f * 4 + r] = -1e30f;
      }
  }
#pragma unroll
  for (int i = 0; i < 16; ++i)
    p[i] = __builtin_amdgcn_exp2f(p[i]);   // scores pre-scaled by log2e; masked -> 0
  // tree-sum (depth 4) instead of 16-deep serial chain
  float q0 = (p[0] + p[1]) + (p[2] + p[3]);
  float q1 = (p[4] + p[5]) + (p[6] + p[7]);
  float q2 = (p[8] + p[9]) + (p[10] + p[11]);
  float q3 = (p[12] + p[13]) + (p[14] + p[15]);
  lp += (q0 + q1) + (q2 + q3);
  // packed f32->bf16: 8 cvt_pk instrs replace the manual add/shift/pack sequence
  union { unsigned u[4]; s8v v; } P0, P1;
#pragma unroll
  for (int j = 0; j < 4; ++j) {
    asm("v_cvt_pk_bf16_f32 %0, %1, %2" : "=v"(P0.u[j]) : "v"(p[2 * j]), "v"(p[2 * j + 1]));
    asm("v_cvt_pk_bf16_f32 %0, %1, %2" : "=v"(P1.u[j]) : "v"(p[8 + 2 * j]), "v"(p[8 + 2 * j + 1]));
  }
  __builtin_amdgcn_s_setprio(1);
  O0 = __builtin_amdgcn_mfma_f32_16x16x32_bf16(P0.v, vf00, O0, 0, 0, 0);
  O0 = __builtin_amdgcn_mfma_f32_16x16x32_bf16(P1.v, vf10, O0, 0, 0, 0);
  O1 = __builtin_amdgcn_mfma_f32_16x16x32_bf16(P0.v, vf01, O1, 0, 0, 0);
  O1 = __builtin_amdgcn_mfma_f32_16x16x32_bf16(P1.v, vf11, O1, 0, 0, 0);
  __builtin_amdgcn_s_setprio(0);
}

__device__ __forceinline__ void attn_write(
    unsigned short* __restrict__ fb, int bh, int qt, int w, int n, int quad,
    float l, const f4v& O0, const f4v& O1) {
  float linv = 1.f / l;
  const int b = bh >> 4, h = bh & 15;
#pragma unroll
  for (int r = 0; r < 4; ++r) {
    float lr = __shfl(linv, quad * 4 + r, 64);
    int qabs = qt * 64 + w * 16 + quad * 4 + r;
    int rglob = b * 2048 + qabs;
    int rt16 = rglob >> 4, m = rglob & 15;
    size_t base = (size_t)(rt16 * 16 + h) * 512;
    fb[base + ((n >> 3) * 16 + m) * 8 + (n & 7)] = f2bf(O0[r] * lr);
    fb[base + ((2 + (n >> 3)) * 16 + m) * 8 + (n & 7)] = f2bf(O1[r] * lr);
  }
}

// grid (16,32): paired q-tiles (qp, 31-qp); direct-global Q frags; dbuf K/V LDS,
// one barrier per k-tile; 2-deep register prefetch pipeline.
__global__ __launch_bounds__(256, 2)
void attn_kernel(const unsigned short* __restrict__ qkv_bf, unsigned short* __restrict__ fb) {
  const int qp = blockIdx.x;   // 0..15
  const int bh = blockIdx.y;   // 0..31
  const int qtA = qp, qtB = 31 - qp;
  const int t = threadIdx.x;
  const int lane = t & 63, w = t >> 6;
  const int n = lane & 15, quad = lane >> 4;
  __shared__ s8v kv_sh[2][512];   // [buf][k:256 | v:256] = 16 KB
  const s8v* Qs = (const s8v*)qkv_bf + (size_t)bh * 32 * 256;
  const s8v* Ks = (const s8v*)(qkv_bf + NQ) + (size_t)bh * 32 * 256;
  const s8v* Vs = (const s8v*)(qkv_bf + 2 * NQ) + (size_t)bh * 32 * 256;
  s8v qfA = Qs[qtA * 256 + w * 64 + lane];
  s8v qfB = Qs[qtB * 256 + w * 64 + lane];
  f4v OA0{}, OA1{}, OB0{}, OB1{};
  float lpA = 0.f, lpB = 0.f;
  s8v k0 = Ks[t], v0 = Vs[t];
  s8v k1, v1;
  if (qtB >= 1) { k1 = Ks[256 + t]; v1 = Vs[256 + t]; }
  for (int kt = 0; kt <= qtB; ++kt) {
    const int c = kt & 1;
    kv_sh[c][t] = k0;
    kv_sh[c][256 + t] = v0;
    __syncthreads();
    k0 = k1; v0 = v1;
    if (kt + 2 <= qtB) {
      k1 = Ks[(kt + 2) * 256 + t];
      v1 = Vs[(kt + 2) * 256 + t];
    }
    const s8v* kb = kv_sh[c];
    const s8v* vb = kb + 256;
    s8v kf0 = kb[lane], kf1 = kb[64 + lane], kf2 = kb[128 + lane], kf3 = kb[192 + lane];
    s8v vf00 = vb[lane], vf01 = vb[64 + lane], vf10 = vb[128 + lane], vf11 = vb[192 + lane];
    if (kt <= qtA)
      tile_step(kt == qtA, w, n, quad, qfA, kf0, kf1, kf2, kf3,
                vf00, vf01, vf10, vf11, lpA, OA0, OA1);
    tile_step(kt == qtB, w, n, quad, qfB, kf0, kf1, kf2, kf3,
              vf00, vf01, vf10, vf11, lpB, OB0, OB1);
  }
  lpA += __shfl_xor(lpA, 16); lpA += __shfl_xor(lpA, 32);
  lpB += __shfl_xor(lpB, 16); lpB += __shfl_xor(lpB, 32);
  attn_write(fb, bh, qtA, w, n, quad, lpA, OA0, OA1);
  attn_write(fb, bh, qtB, w, n, quad, lpB, OB0, OB1);
}

// ================= K4: output projection: LDS-staged-B MFMA GEMM =================
// grid (64,8): each block 64 rows x 64 cols; B (Wo frags) staged 4 KB/kc, dbuf.
__global__ __launch_bounds__(256)
void outproj_mfma_kernel(const unsigned short* __restrict__ fb_u,
                         const unsigned short* __restrict__ wob_u,
                         const float* __restrict__ bo,
                         float* __restrict__ out) {
  const int rt64 = blockIdx.x;  // 64
  const int jt = blockIdx.y;    // 8 (4 n-frags each)
  const int t = threadIdx.x;
  const int lane = t & 63, w = t >> 6;
  const int n = lane & 15, quad = lane >> 4;
  const s8v* fbv = (const s8v*)fb_u;
  const int rt16 = rt64 * 4 + w;
  __shared__ __align__(16) unsigned short bsh[2][2048];  // 2 x 4 KB
  auto stage = [&](int buf, int kc) {
    const char* src = (const char*)wob_u + ((size_t)(kc * 32 + jt * 4) * 64) * 16
                      + (size_t)w * 1024 + (size_t)lane * 16;
    char* dst = (char*)bsh[buf] + w * 1024;
    __builtin_amdgcn_global_load_lds(
        (const __attribute__((address_space(1))) void*)src,
        (__attribute__((address_space(3))) void*)dst, 16, 0, 0);
  };
  f4v acc[4] = {};
  s8v a_cur = fbv[((size_t)rt16 * 16 + 0) * 64 + lane];
  stage(0, 0);
  __syncthreads();
  for (int kc = 0; kc < 16; ++kc) {
    const int buf = kc & 1;
    if (kc < 15) stage(buf ^ 1, kc + 1);
    s8v a_nxt;
    if (kc < 15) a_nxt = fbv[((size_t)rt16 * 16 + kc + 1) * 64 + lane];
    const s8v* bb = (const s8v*)bsh[buf];
#pragma unroll
    for (int i = 0; i < 4; ++i)
      acc[i] = __builtin_amdgcn_mfma_f32_16x16x32_bf16(a_cur, bb[i * 64 + lane], acc[i], 0, 0, 0);
    __syncthreads();
    if (kc < 15) a_cur = a_nxt;
  }
#pragma unroll
  for (int i = 0; i < 4; ++i) {
    const int j = jt * 64 + i * 16 + n;
    const float bias = bo[j];
#pragma unroll
    for (int reg = 0; reg < 4; ++reg) {
      int r = rt64 * 64 + w * 16 + quad * 4 + reg;
      out[(size_t)r * INn + j] = acc[i][reg] + bias;
    }
  }
}

extern "C" void kernel_launch(void* const* d_in, const int* in_sizes, int n_in,
                              void* d_out, int out_size, void* d_ws, size_t ws_size,
                              hipStream_t stream) {
  const float* x  = (const float*)d_in[0];
  const float* Wl = (const float*)d_in[1];
  const float* bl = (const float*)d_in[2];
  const float* Wq = (const float*)d_in[3];
  const float* Wk = (const float*)d_in[4];
  const float* Wv = (const float*)d_in[5];
  const float* Wo = (const float*)d_in[6];
  const float* bo = (const float*)d_in[7];
  float* ws = (float*)d_ws;
  float* out = (float*)d_out;
  unsigned short* wbb = (unsigned short*)(ws + OFF_WBB);
  float*          beff = ws + OFF_BEFF;
  unsigned short* qkv = (unsigned short*)(ws + OFF_QKV);
  unsigned short* xb  = (unsigned short*)(ws + OFF_XB);
  unsigned short* fb  = (unsigned short*)(ws + OFF_FB);
  unsigned short* wob = (unsigned short*)(ws + OFF_WOB);

  stage1_kernel<<<dim3(1456), 256, 0, stream>>>(Wl, bl, Wq, Wk, Wv, x, Wo, wbb, beff, xb, wob);
  qkv_mfma_kernel<<<dim3(32, Hn), 256, 0, stream>>>(xb, wbb, beff, qkv);
  attn_kernel<<<dim3(16, 32), 256, 0, stream>>>(qkv, fb);
  outproj_mfma_kernel<<<dim3(64, 8), 256, 0, stream>>>(fb, wob, bo, out);
}

// Round 5
// 130.543 us; speedup vs baseline: 1.1469x; 1.0124x over previous
//
#include <hip/hip_runtime.h>
#include <math.h>

namespace {
constexpr int Bn = 2, Sn = 2048, INn = 512, HDn = 32, Hn = 16;
constexpr int NQ = Bn * Hn * Sn * HDn;           // 2097152 bf16 elems per Q/K/V tensor
// ws offsets in FLOAT units — all regions DISJOINT
constexpr int OFF_WBB = 2490368;    // Weff B-frags bf16: 786432 bf16 -> 393216 fl
constexpr int OFF_BEFF = 2883584;   // 1536 fl
constexpr int OFF_QKV = 2885120;    // Q,K,V swizzled bf16: 3*2097152 -> 3145728 fl
constexpr int OFF_XB = 6030848;     // x A-frags bf16 -> 1048576 fl
constexpr int OFF_FB = 7079424;     // F A-frags bf16 -> 1048576 fl
constexpr int OFF_WOB = 8128000;    // Wo B-frags bf16 -> 131072 fl
constexpr float LOG2E = 1.44269504f;
}

typedef __attribute__((ext_vector_type(8))) short s8v;   // 8 bf16 in 4 VGPRs
typedef __attribute__((ext_vector_type(4))) float f4v;   // MFMA accumulator

__device__ __forceinline__ unsigned short f2bf(float x) {
  unsigned u = __float_as_uint(x);
  return (unsigned short)((u + 0x8000u) >> 16);
}

// ========== K1: weff_direct (LDS-staged MFMA) + beff + xconv + woconv (flat 1456) ==========
__global__ __launch_bounds__(256)
void stage1_kernel(const float* __restrict__ Wl, const float* __restrict__ bl,
                   const float* __restrict__ Wq, const float* __restrict__ Wk,
                   const float* __restrict__ Wv,
                   const float* __restrict__ x, const float* __restrict__ Wo,
                   unsigned short* __restrict__ wbb, float* __restrict__ beff,
                   unsigned short* __restrict__ xb, unsigned short* __restrict__ wob) {
  const int bid = blockIdx.x;
  const int t = threadIdx.x;
  __shared__ __align__(16) unsigned short ws_sh[8192];   // 16 KB union
  if (bid < 256) {
    // ---- weff_direct ----
    const int bx = bid & 15, h = bid >> 4;
    const int lane = t & 63, w = t >> 6;
    const int n = lane & 15, quad = lane >> 4;
    const int nt0 = (w >> 1) * 3;
    unsigned short* a_sh = ws_sh;          // [4][512]  (it_sub*2+kc_sub)
    unsigned short* b_sh = ws_sh + 2048;   // [12][512] (kc_sub*6+nt)
    f4v acc[3] = {};
    for (int ot = 0; ot < 8; ++ot) {
      __syncthreads();   // previous chunk's reads done
      // stage A: Wl[h][o(64)][i(32)] -> transposed bf16 A-frags
#pragma unroll
      for (int k = 0; k < 8; ++k) {
        int idx = t + k * 256;
        int ol = idx >> 5, il = idx & 31;
        float v = Wl[(size_t)(h * INn + ot * 64 + ol) * INn + bx * 32 + il];
        int dst = (((il >> 4) * 2 + (ol >> 5)) * 64 + ((ol >> 3) & 3) * 16 + (il & 15)) * 8 + (ol & 7);
        a_sh[dst] = f2bf(v);
      }
      // stage B: Wq/Wk/Wv[h][o(64)][32] -> bf16 B-frags (K pre-scaled by log2e)
#pragma unroll
      for (int which = 0; which < 3; ++which) {
        const float* Wx = which == 0 ? Wq : (which == 1 ? Wk : Wv);
        const float scale = (which == 1) ? LOG2E : 1.0f;
#pragma unroll
        for (int k = 0; k < 8; ++k) {
          int idx = t + k * 256;
          int ol = idx >> 5, dd = idx & 31;
          float v = Wx[(size_t)(h * INn + ot * 64 + ol) * HDn + dd] * scale;
          int nt = which * 2 + (dd >> 4);
          int dst = (((ol >> 5) * 6 + nt) * 64 + ((ol >> 3) & 3) * 16 + (dd & 15)) * 8 + (ol & 7);
          b_sh[dst] = f2bf(v);
        }
      }
      __syncthreads();
      const s8v* av = (const s8v*)a_sh;
      const s8v* bv = (const s8v*)b_sh;
#pragma unroll
      for (int kc_sub = 0; kc_sub < 2; ++kc_sub) {
        s8v a = av[((w & 1) * 2 + kc_sub) * 64 + lane];
#pragma unroll
        for (int q = 0; q < 3; ++q)
          acc[q] = __builtin_amdgcn_mfma_f32_16x16x32_bf16(
              a, bv[(kc_sub * 6 + nt0 + q) * 64 + lane], acc[q], 0, 0, 0);
      }
    }
    // epilogue: C -> LDS (stride 97) -> B-frag coalesced stores
    __syncthreads();
    unsigned short* clds = ws_sh;   // 32*97 ushort
#pragma unroll
    for (int q = 0; q < 3; ++q)
#pragma unroll
      for (int reg = 0; reg < 4; ++reg) {
        int i_local = (w & 1) * 16 + quad * 4 + reg;
        int n96 = (nt0 + q) * 16 + n;
        clds[i_local * 97 + n96] = f2bf(acc[q][reg]);
      }
    __syncthreads();
    s8v* wbbv = (s8v*)wbb;
    for (int nt = w; nt < 6; nt += 4) {
      s8v v;
#pragma unroll
      for (int j = 0; j < 8; j++)
        v[j] = (short)clds[((lane >> 4) * 8 + j) * 97 + nt * 16 + (lane & 15)];
      wbbv[((h * 16 + bx) * 6 + nt) * 64 + lane] = v;
    }
  } else if (bid < 304) {
    // ---- beff ----
    const int v0 = bid - 256;         // 0..47
    const int h = v0 & 15, which = v0 >> 4;
    const float* Wx = which == 0 ? Wq : (which == 1 ? Wk : Wv);
    const float scale = (which == 1) ? LOG2E : 1.0f;
    const int d = t & 31, oc = t >> 5;
    float p = 0.f;
    for (int k = 0; k < 64; k++) {
      int o = oc * 64 + k;
      p += bl[h * INn + o] * Wx[(h * INn + o) * HDn + d];
    }
    float* red = (float*)ws_sh;
    red[t] = p;
    __syncthreads();
    if (t < 32) {
      float s = 0.f;
#pragma unroll
      for (int k = 0; k < 8; k++) s += red[t + 32 * k];
      beff[which * (Hn * HDn) + h * HDn + t] = s * scale;
    }
  } else if (bid < 1328) {
    // ---- xconv: x -> A-frags ----
    const int tid = (bid - 304) * 256 + t;      // 0..262143
    const int lane = tid & 63;
    const int rk = tid >> 6;
    const int rt16 = rk >> 4, kc = rk & 15;
    const float* src = x + (size_t)(rt16 * 16 + (lane & 15)) * INn + kc * 32 + (lane >> 4) * 8;
    unsigned short* dst = xb + (size_t)tid * 8;
#pragma unroll
    for (int j = 0; j < 8; j++) dst[j] = f2bf(src[j]);
  } else {
    // ---- woconv: Wo -> B-frags ----
    const int tid = (bid - 1328) * 256 + t;     // 0..32767
    const int lane = tid & 63;
    const int kn = tid >> 6;
    const int kc = kn >> 5, nt = kn & 31;
    const float* src = Wo + (size_t)(nt * 16 + (lane & 15)) * INn + kc * 32 + (lane >> 4) * 8;
    unsigned short* dst = wob + (size_t)tid * 8;
#pragma unroll
    for (int j = 0; j < 8; j++) dst[j] = f2bf(src[j]);
  }
}

// ================= K2: QKV projection: LDS-staged-B MFMA GEMM =================
// grid (32,16): each block does 128 rows (2 row-tiles per wave) of one head.
// B (Weff frags, 96 KB/head) staged once per block via global_load_lds, dbuf 2x12KB.
__global__ __launch_bounds__(256)
void qkv_mfma_kernel(const unsigned short* __restrict__ xb_u,
                     const unsigned short* __restrict__ wbb_u,
                     const float* __restrict__ beff,
                     unsigned short* __restrict__ qkv) {
  const int rt32 = blockIdx.x;  // 0..31 -> rows [rt32*128, +128)
  const int h = blockIdx.y;     // 16
  const int t = threadIdx.x;
  const int lane = t & 63, w = t >> 6;
  const int n = lane & 15, quad = lane >> 4;
  const s8v* xbv = (const s8v*)xb_u;
  __shared__ __align__(16) unsigned short bsh[2][6144];   // 2 bufs x 12 KB (2 kc x 6 frags)
  const int rtA = rt32 * 8 + w;        // half-0 row-tile of this wave
  const int rtB = rt32 * 8 + 4 + w;    // half-1 row-tile

  const char* wsrc = (const char*)wbb_u + (size_t)h * 16 * 6 * 64 * 16;
  // stage chunk c (kc = 2c,2c+1): 12288 B; lds dest = wave-uniform base + lane*16 (linear)
  auto stage = [&](int buf, int c) {
    const char* src = wsrc + (size_t)c * 12288 + (size_t)lane * 16;
    char* dst = (char*)bsh[buf];
#pragma unroll
    for (int j = 0; j < 3; ++j) {
      int off = (w * 3 + j) * 1024;
      __builtin_amdgcn_global_load_lds(
          (const __attribute__((address_space(1))) void*)(src + off),
          (__attribute__((address_space(3))) void*)(dst + off), 16, 0, 0);
    }
  };

  f4v acc[2][6] = {};
  s8v a0[2], a1[2];
#pragma unroll
  for (int ks = 0; ks < 2; ++ks) {
    a0[ks] = xbv[((size_t)rtA * 16 + ks) * 64 + lane];
    a1[ks] = xbv[((size_t)rtB * 16 + ks) * 64 + lane];
  }
  stage(0, 0);
  __syncthreads();   // implicit vmcnt(0) drain -> buf0 ready
  for (int c = 0; c < 8; ++c) {
    const int buf = c & 1;
    if (c < 7) stage(buf ^ 1, c + 1);
    s8v na0[2], na1[2];
    if (c < 7) {
#pragma unroll
      for (int ks = 0; ks < 2; ++ks) {
        int kc = (c + 1) * 2 + ks;
        na0[ks] = xbv[((size_t)rtA * 16 + kc) * 64 + lane];
        na1[ks] = xbv[((size_t)rtB * 16 + kc) * 64 + lane];
      }
    }
    const s8v* bb = (const s8v*)bsh[buf];
#pragma unroll
    for (int ks = 0; ks < 2; ++ks) {
#pragma unroll
      for (int nt = 0; nt < 6; ++nt) {
        s8v b = bb[(ks * 6 + nt) * 64 + lane];
        acc[0][nt] = __builtin_amdgcn_mfma_f32_16x16x32_bf16(a0[ks], b, acc[0][nt], 0, 0, 0);
        acc[1][nt] = __builtin_amdgcn_mfma_f32_16x16x32_bf16(a1[ks], b, acc[1][nt], 0, 0, 0);
      }
    }
    __syncthreads();   // drains next-chunk stage; protects WAR on buf^1
    if (c < 7) {
#pragma unroll
      for (int ks = 0; ks < 2; ++ks) { a0[ks] = na0[ks]; a1[ks] = na1[ks]; }
    }
  }
  // epilogue: reuse bsh[0] (12 KB) as swizzle-assembly LDS, one 64-row group per half
  unsigned short* eld = bsh[0];
  const s8v* eldv = (const s8v*)eld;
  for (int half = 0; half < 2; ++half) {
    __syncthreads();   // prior reads of bsh/eld complete
#pragma unroll
    for (int nt = 0; nt < 6; ++nt) {
      const int which = nt >> 1;
      const int dd = (nt & 1) * 16 + n;
      const float bias = beff[which * 512 + h * 32 + dd];
#pragma unroll
      for (int reg = 0; reg < 4; ++reg) {
        const int kl = w * 16 + quad * 4 + reg;
        unsigned short val = f2bf(acc[half][nt][reg] + bias);
        int off;
        if (which == 0) {
          off = (((kl >> 4) * 4 + (dd >> 3)) * 16 + (kl & 15)) * 8 + (dd & 7);
        } else if (which == 1) {
          int f = ((kl >> 5) << 1) | ((kl >> 2) & 1);
          int mm = ((kl >> 3) & 3) * 4 + (kl & 3);
          off = ((f * 4 + (dd >> 3)) * 16 + mm) * 8 + (dd & 7);
        } else {
          off = ((((kl >> 5) * 2 + (dd >> 4)) * 4 + ((kl >> 3) & 3)) * 16 + (dd & 15)) * 8 + (kl & 7);
        }
        eld[which * 2048 + off] = val;
      }
    }
    __syncthreads();
    const int rt64 = rt32 * 2 + half;
    const int b = rt64 >> 5;
    const int ts = rt64 & 31;
    const size_t tilebase = ((size_t)((b * Hn + h) * 32) + ts) * 2048;  // bf16 units
#pragma unroll
    for (int cc = 0; cc < 3; ++cc) {
      int idx = cc * 256 + t;            // 0..767
      int which = idx >> 8, k8 = idx & 255;
      *((s8v*)(qkv + (size_t)which * NQ + tilebase) + k8) = eldv[idx];
    }
  }
}

// ================= K3: MFMA flash attention, fixed-base softmax =================
__device__ __forceinline__ void tile_step(
    bool diag, int w, int n, int quad,
    const s8v& qf, const s8v& kf0, const s8v& kf1, const s8v& kf2, const s8v& kf3,
    const s8v& vf00, const s8v& vf01, const s8v& vf10, const s8v& vf11,
    float& lp, f4v& O0, f4v& O1) {
  const f4v zero{};
  __builtin_amdgcn_s_setprio(1);
  f4v s0 = __builtin_amdgcn_mfma_f32_16x16x32_bf16(kf0, qf, zero, 0, 0, 0);
  f4v s1 = __builtin_amdgcn_mfma_f32_16x16x32_bf16(kf1, qf, zero, 0, 0, 0);
  f4v s2 = __builtin_amdgcn_mfma_f32_16x16x32_bf16(kf2, qf, zero, 0, 0, 0);
  f4v s3 = __builtin_amdgcn_mfma_f32_16x16x32_bf16(kf3, qf, zero, 0, 0, 0);
  __builtin_amdgcn_s_setprio(0);
  float p[16];
#pragma unroll
  for (int r = 0; r < 4; ++r) {
    p[0 * 4 + r] = s0[r];
    p[1 * 4 + r] = s1[r];
    p[2 * 4 + r] = s2[r];
    p[3 * 4 + r] = s3[r];
  }
  if (diag) {
    int qa = w * 16 + n;
#pragma unroll
    for (int f = 0; f < 4; ++f)
#pragma unroll
      for (int r = 0; r < 4; ++r) {
        int ka = ((f >> 1) << 5) + quad * 8 + ((f & 1) << 2) + r;
        if (ka > qa) p[f * 4 + r] = -1e30f;
      }
  }
#pragma unroll
  for (int i = 0; i < 16; ++i)
    p[i] = __builtin_amdgcn_exp2f(p[i]);   // scores pre-scaled by log2e; masked -> 0
  // tree-sum (depth 4) instead of 16-deep serial chain
  float q0 = (p[0] + p[1]) + (p[2] + p[3]);
  float q1 = (p[4] + p[5]) + (p[6] + p[7]);
  float q2 = (p[8] + p[9]) + (p[10] + p[11]);
  float q3 = (p[12] + p[13]) + (p[14] + p[15]);
  lp += (q0 + q1) + (q2 + q3);
  // packed f32->bf16: 8 cvt_pk instrs replace the manual add/shift/pack sequence
  union { unsigned u[4]; s8v v; } P0, P1;
#pragma unroll
  for (int j = 0; j < 4; ++j) {
    asm("v_cvt_pk_bf16_f32 %0, %1, %2" : "=v"(P0.u[j]) : "v"(p[2 * j]), "v"(p[2 * j + 1]));
    asm("v_cvt_pk_bf16_f32 %0, %1, %2" : "=v"(P1.u[j]) : "v"(p[8 + 2 * j]), "v"(p[8 + 2 * j + 1]));
  }
  __builtin_amdgcn_s_setprio(1);
  O0 = __builtin_amdgcn_mfma_f32_16x16x32_bf16(P0.v, vf00, O0, 0, 0, 0);
  O0 = __builtin_amdgcn_mfma_f32_16x16x32_bf16(P1.v, vf10, O0, 0, 0, 0);
  O1 = __builtin_amdgcn_mfma_f32_16x16x32_bf16(P0.v, vf01, O1, 0, 0, 0);
  O1 = __builtin_amdgcn_mfma_f32_16x16x32_bf16(P1.v, vf11, O1, 0, 0, 0);
  __builtin_amdgcn_s_setprio(0);
}

__device__ __forceinline__ void attn_write(
    unsigned short* __restrict__ fb, int bh, int qt, int w, int n, int quad,
    float l, const f4v& O0, const f4v& O1) {
  float linv = 1.f / l;
  const int b = bh >> 4, h = bh & 15;
#pragma unroll
  for (int r = 0; r < 4; ++r) {
    float lr = __shfl(linv, quad * 4 + r, 64);
    int qabs = qt * 64 + w * 16 + quad * 4 + r;
    int rglob = b * 2048 + qabs;
    int rt16 = rglob >> 4, m = rglob & 15;
    size_t base = (size_t)(rt16 * 16 + h) * 512;
    fb[base + ((n >> 3) * 16 + m) * 8 + (n & 7)] = f2bf(O0[r] * lr);
    fb[base + ((2 + (n >> 3)) * 16 + m) * 8 + (n & 7)] = f2bf(O1[r] * lr);
  }
}

// 1D grid (512) + bijective XCD swizzle: all 16 qp-blocks of a bh land on one
// XCD -> its 512 KB K/V stays L2-resident (L3 re-reads 418 MB -> ~16 MB).
// Paired q-tiles (qp, 31-qp); direct-global Q frags; dbuf K/V LDS,
// one barrier per k-tile; 2-deep register prefetch pipeline.
__global__ __launch_bounds__(256, 2)
void attn_kernel(const unsigned short* __restrict__ qkv_bf, unsigned short* __restrict__ fb) {
  const int bid = blockIdx.x;                 // 0..511, 512 % 8 == 0
  const int g = (bid & 7) * 64 + (bid >> 3);  // XCD (bid&7) owns g in [64x, 64x+63]
  const int qp = g & 15;      // 0..15
  const int bh = g >> 4;      // 0..31  (4 consecutive bh per XCD)
  const int qtA = qp, qtB = 31 - qp;
  const int t = threadIdx.x;
  const int lane = t & 63, w = t >> 6;
  const int n = lane & 15, quad = lane >> 4;
  __shared__ s8v kv_sh[2][512];   // [buf][k:256 | v:256] = 16 KB
  const s8v* Qs = (const s8v*)qkv_bf + (size_t)bh * 32 * 256;
  const s8v* Ks = (const s8v*)(qkv_bf + NQ) + (size_t)bh * 32 * 256;
  const s8v* Vs = (const s8v*)(qkv_bf + 2 * NQ) + (size_t)bh * 32 * 256;
  s8v qfA = Qs[qtA * 256 + w * 64 + lane];
  s8v qfB = Qs[qtB * 256 + w * 64 + lane];
  f4v OA0{}, OA1{}, OB0{}, OB1{};
  float lpA = 0.f, lpB = 0.f;
  s8v k0 = Ks[t], v0 = Vs[t];
  s8v k1, v1;
  if (qtB >= 1) { k1 = Ks[256 + t]; v1 = Vs[256 + t]; }
  for (int kt = 0; kt <= qtB; ++kt) {
    const int c = kt & 1;
    kv_sh[c][t] = k0;
    kv_sh[c][256 + t] = v0;
    __syncthreads();
    k0 = k1; v0 = v1;
    if (kt + 2 <= qtB) {
      k1 = Ks[(kt + 2) * 256 + t];
      v1 = Vs[(kt + 2) * 256 + t];
    }
    const s8v* kb = kv_sh[c];
    const s8v* vb = kb + 256;
    s8v kf0 = kb[lane], kf1 = kb[64 + lane], kf2 = kb[128 + lane], kf3 = kb[192 + lane];
    s8v vf00 = vb[lane], vf01 = vb[64 + lane], vf10 = vb[128 + lane], vf11 = vb[192 + lane];
    if (kt <= qtA)
      tile_step(kt == qtA, w, n, quad, qfA, kf0, kf1, kf2, kf3,
                vf00, vf01, vf10, vf11, lpA, OA0, OA1);
    tile_step(kt == qtB, w, n, quad, qfB, kf0, kf1, kf2, kf3,
              vf00, vf01, vf10, vf11, lpB, OB0, OB1);
  }
  lpA += __shfl_xor(lpA, 16); lpA += __shfl_xor(lpA, 32);
  lpB += __shfl_xor(lpB, 16); lpB += __shfl_xor(lpB, 32);
  attn_write(fb, bh, qtA, w, n, quad, lpA, OA0, OA1);
  attn_write(fb, bh, qtB, w, n, quad, lpB, OB0, OB1);
}

// ================= K4: output projection: LDS-staged-B MFMA GEMM =================
// grid (64,8): each block 64 rows x 64 cols; B (Wo frags) staged 4 KB/kc, dbuf.
__global__ __launch_bounds__(256)
void outproj_mfma_kernel(const unsigned short* __restrict__ fb_u,
                         const unsigned short* __restrict__ wob_u,
                         const float* __restrict__ bo,
                         float* __restrict__ out) {
  const int rt64 = blockIdx.x;  // 64
  const int jt = blockIdx.y;    // 8 (4 n-frags each)
  const int t = threadIdx.x;
  const int lane = t & 63, w = t >> 6;
  const int n = lane & 15, quad = lane >> 4;
  const s8v* fbv = (const s8v*)fb_u;
  const int rt16 = rt64 * 4 + w;
  __shared__ __align__(16) unsigned short bsh[2][2048];  // 2 x 4 KB
  auto stage = [&](int buf, int kc) {
    const char* src = (const char*)wob_u + ((size_t)(kc * 32 + jt * 4) * 64) * 16
                      + (size_t)w * 1024 + (size_t)lane * 16;
    char* dst = (char*)bsh[buf] + w * 1024;
    __builtin_amdgcn_global_load_lds(
        (const __attribute__((address_space(1))) void*)src,
        (__attribute__((address_space(3))) void*)dst, 16, 0, 0);
  };
  f4v acc[4] = {};
  s8v a_cur = fbv[((size_t)rt16 * 16 + 0) * 64 + lane];
  stage(0, 0);
  __syncthreads();
  for (int kc = 0; kc < 16; ++kc) {
    const int buf = kc & 1;
    if (kc < 15) stage(buf ^ 1, kc + 1);
    s8v a_nxt;
    if (kc < 15) a_nxt = fbv[((size_t)rt16 * 16 + kc + 1) * 64 + lane];
    const s8v* bb = (const s8v*)bsh[buf];
#pragma unroll
    for (int i = 0; i < 4; ++i)
      acc[i] = __builtin_amdgcn_mfma_f32_16x16x32_bf16(a_cur, bb[i * 64 + lane], acc[i], 0, 0, 0);
    __syncthreads();
    if (kc < 15) a_cur = a_nxt;
  }
#pragma unroll
  for (int i = 0; i < 4; ++i) {
    const int j = jt * 64 + i * 16 + n;
    const float bias = bo[j];
#pragma unroll
    for (int reg = 0; reg < 4; ++reg) {
      int r = rt64 * 64 + w * 16 + quad * 4 + reg;
      out[(size_t)r * INn + j] = acc[i][reg] + bias;
    }
  }
}

extern "C" void kernel_launch(void* const* d_in, const int* in_sizes, int n_in,
                              void* d_out, int out_size, void* d_ws, size_t ws_size,
                              hipStream_t stream) {
  const float* x  = (const float*)d_in[0];
  const float* Wl = (const float*)d_in[1];
  const float* bl = (const float*)d_in[2];
  const float* Wq = (const float*)d_in[3];
  const float* Wk = (const float*)d_in[4];
  const float* Wv = (const float*)d_in[5];
  const float* Wo = (const float*)d_in[6];
  const float* bo = (const float*)d_in[7];
  float* ws = (float*)d_ws;
  float* out = (float*)d_out;
  unsigned short* wbb = (unsigned short*)(ws + OFF_WBB);
  float*          beff = ws + OFF_BEFF;
  unsigned short* qkv = (unsigned short*)(ws + OFF_QKV);
  unsigned short* xb  = (unsigned short*)(ws + OFF_XB);
  unsigned short* fb  = (unsigned short*)(ws + OFF_FB);
  unsigned short* wob = (unsigned short*)(ws + OFF_WOB);

  stage1_kernel<<<dim3(1456), 256, 0, stream>>>(Wl, bl, Wq, Wk, Wv, x, Wo, wbb, beff, xb, wob);
  qkv_mfma_kernel<<<dim3(32, Hn), 256, 0, stream>>>(xb, wbb, beff, qkv);
  attn_kernel<<<dim3(512), 256, 0, stream>>>(qkv, fb);
  outproj_mfma_kernel<<<dim3(64, 8), 256, 0, stream>>>(fb, wob, bo, out);
}